// Round 4
// baseline (962.489 us; speedup 1.0000x reference)
//
#include <hip/hip_runtime.h>
#include <math.h>

#define B_   16
#define C_   32
#define N_   2048
#define K_   24
#define BNK_ (B_*N_*K_)      /* 786432 */

/* ws layout (float/int32 units), ~14.0 MB total */
#define WS_XT   0u           /* xt[b][n][c]  : 1048576 f            */
#define WS_XXD  1048576u     /* xx[b][n] fp64: 32768 d = 65536 f    */
#define WS_XXF  1114112u     /* xx[b][n] fp32: 32768 f              */
#define WS_IDX  1146880u     /* idx[b][n][k] : 786432 i             */
#define WS_D2   1933312u     /* d2 [b][n][k] : 786432 f             */
#define WS_ATT  2719744u     /* att[b][n][k] : 786432 f             */
#define WS_ST   3506176u     /* sum/sumsq    : 128 f                */
#define WS_AB   3506304u     /* BN A,B       : 128 f                */

/* ---------------- K0: transpose x -> xt, row norms (fp64+fp32), zero stats */
__global__ __launch_bounds__(256) void k0_prep(const float* __restrict__ x,
                                               float* __restrict__ ws) {
  int t = blockIdx.x * 256 + threadIdx.x;     /* 0..32767 = b*2048+n */
  int b = t >> 11, n = t & 2047;
  const float* xp = x + ((size_t)b * C_ * N_) + n;
  float* xt = ws + WS_XT + (size_t)t * C_;
  double s = 0.0;
#pragma unroll
  for (int c = 0; c < C_; ++c) {
    float v = xp[(size_t)c * N_];
    xt[c] = v;
    s = fma((double)v, (double)v, s);
  }
  ((double*)(ws + WS_XXD))[t] = s;
  ws[WS_XXF + t] = (float)s;
  if (t < 128) ws[WS_ST + t] = 0.f;
}

/* ---------------- K1: exact top-24 neighbors per (b,n) --------------------
   Phase 1: fp32 scan, per-quarter top-24 via med3 shift-insert (branchless,
            1 instr/entry), 11-bit m packed in fp32 mantissa low bits.
   Phase 3: each wave fp64-re-ranks its own 24 candidates (exact products),
            m packed in fp64 mantissa low bits (2^-41, ordering-safe).
   Phase 4: wave0 4-way-merges sorted fp64 lists -> exact global top-24.   */
__global__ __launch_bounds__(256, 2) void k1_topk(float* __restrict__ ws) {
  __shared__ double pv[4][64][25];
  const float* xt = ws + WS_XT;
  const double* xxd = (const double*)(ws + WS_XXD);
  const int lane = threadIdx.x & 63;
  const int wv   = __builtin_amdgcn_readfirstlane(threadIdx.x >> 6);
  const int g = blockIdx.x;          /* 0..511 */
  const int b = g >> 5;
  const int n = ((g & 31) << 6) + lane;
  const int bn = (b << 11) + n;

  float xn[C_];
  {
    const float4* p = (const float4*)(xt + (size_t)bn * C_);
#pragma unroll
    for (int q = 0; q < 8; ++q) {
      float4 v = p[q];
      xn[4*q] = v.x; xn[4*q+1] = v.y; xn[4*q+2] = v.z; xn[4*q+3] = v.w;
    }
  }

  float val[K_];
#pragma unroll
  for (int j = 0; j < K_; ++j) val[j] = -3.4e38f;

  const float* mrow = xt + ((size_t)((b << 11) + (wv << 9))) * C_;  /* uniform */
  const float* xxf  = ws + WS_XXF + (b << 11) + (wv << 9);          /* uniform */

  /* ---- Phase 1: fp32 scan of this wave's 512 candidates ---- */
#pragma unroll 2
  for (int mm = 0; mm < 512; ++mm) {
    const float* r = mrow + (size_t)mm * C_;   /* wave-uniform -> s_load */
    float a0 = 0.f, a1 = 0.f, a2 = 0.f, a3 = 0.f;
#pragma unroll
    for (int c = 0; c < 8; ++c) {
      a0 = fmaf(xn[c     ], r[c     ], a0);
      a1 = fmaf(xn[c + 8 ], r[c + 8 ], a1);
      a2 = fmaf(xn[c + 16], r[c + 16], a2);
      a3 = fmaf(xn[c + 24], r[c + 24], a3);
    }
    float s = 2.f * ((a0 + a1) + (a2 + a3)) - xxf[mm];
    /* pack 11-bit global m into mantissa low bits (|ds| ~ 2^-12 rel: safe) */
    int sb = (__float_as_int(s) & ~2047) | ((wv << 9) + mm);
    float sp = __int_as_float(sb);
    /* branchless med3 shift-insert into descending sorted val[0..23] */
#pragma unroll
    for (int j = K_ - 1; j >= 1; --j)
      val[j] = __builtin_amdgcn_fmed3f(val[j - 1], val[j], sp);
    val[0] = fmaxf(val[0], sp);
  }

  /* ---- Phase 3: fp64 re-rank of this wave's 24 candidates ---- */
  double xnd[C_];
#pragma unroll
  for (int c = 0; c < C_; ++c) xnd[c] = (double)xn[c];

  double dl[K_];
#pragma unroll
  for (int j = 0; j < K_; ++j) dl[j] = -1.7e308;

#pragma unroll 1
  for (int j = 0; j < K_; ++j) {
    const int m = __float_as_int(val[j]) & 2047;      /* per-lane index */
    const float* r = xt + ((size_t)((b << 11) + m)) * C_;
    double a0 = 0.0, a1 = 0.0;
#pragma unroll
    for (int c = 0; c < 16; ++c) {
      a0 = fma((double)r[c],      xnd[c],      a0);
      a1 = fma((double)r[c + 16], xnd[c + 16], a1);
    }
    double s = 2.0 * (a0 + a1) - xxd[(b << 11) + m];
    long long bits = (__double_as_longlong(s) & 0xFFFFFFFFFFFFF800ll) | (long long)m;
    double sp = __longlong_as_double(bits);
    /* branchless shift-insert into descending dl[0..23] */
    bool c2 = true;
#pragma unroll
    for (int jj = K_ - 1; jj >= 1; --jj) {
      bool c1 = sp > dl[jj - 1];
      dl[jj] = c1 ? dl[jj - 1] : (c2 ? sp : dl[jj]);
      c2 = c1;
    }
    if (c2) dl[0] = sp;
  }
#pragma unroll
  for (int j = 0; j < K_; ++j) pv[wv][lane][j] = dl[j];
  pv[wv][lane][K_] = -1.7e308;   /* sentinel */
  __syncthreads();

  /* ---- Phase 4: wave0 merges 4 sorted lists -> exact top-24 ---- */
  if (wv == 0) {
    int i0 = 0, i1 = 0, i2 = 0, i3 = 0;
    double v0 = pv[0][lane][0], v1 = pv[1][lane][0], v2 = pv[2][lane][0], v3 = pv[3][lane][0];
    int*   op = (int*)ws + WS_IDX + (size_t)bn * K_;
    float* dp = ws + WS_D2 + (size_t)bn * K_;
    const double xxn = xxd[bn];
#pragma unroll 1
    for (int rr = 0; rr < K_; ++rr) {
      double bv = v0; int bq = 0;
      if (v1 > bv) { bv = v1; bq = 1; }
      if (v2 > bv) { bv = v2; bq = 2; }
      if (v3 > bv) { bv = v3; bq = 3; }
      long long bl = __double_as_longlong(bv);
      op[rr] = (int)(bl & 0x7FFll);
      dp[rr] = (float)(xxn - __longlong_as_double(bl & 0xFFFFFFFFFFFFF800ll));
      if      (bq == 0) { ++i0; v0 = pv[0][lane][i0]; }
      else if (bq == 1) { ++i1; v1 = pv[1][lane][i1]; }
      else if (bq == 2) { ++i2; v2 = pv[2][lane][i2]; }
      else              { ++i3; v3 = pv[3][lane][i3]; }
    }
  }
}

/* ---------------- K2a: attention MLP + softmax (lane = point) ------------- */
__global__ __launch_bounds__(256) void k2a_att(const float* __restrict__ w1,
                                               const float* __restrict__ w2,
                                               float* __restrict__ ws) {
  __shared__ float lgs[64][25];
  const int lane = threadIdx.x & 63;
  const int wv   = threadIdx.x >> 6;
  const int bn   = blockIdx.x * 64 + lane;
  const int b    = bn >> 11;
  const float* xt = ws + WS_XT;

  int   mk[6];
  float dd[6];
  {
    const int*   ip = (const int*)ws + WS_IDX + (size_t)bn * K_;
    const float* dp = ws + WS_D2 + (size_t)bn * K_;
#pragma unroll
    for (int kk = 0; kk < 6; ++kk) { mk[kk] = ip[wv * 6 + kk]; dd[kk] = dp[wv * 6 + kk]; }
  }

  float cent[C_];
  {
    const float4* cp = (const float4*)(xt + (size_t)bn * C_);
#pragma unroll
    for (int q = 0; q < 8; ++q) {
      float4 v = cp[q];
      cent[4*q] = v.x; cent[4*q+1] = v.y; cent[4*q+2] = v.z; cent[4*q+3] = v.w;
    }
  }

  float base[64];
#pragma unroll 4
  for (int o = 0; o < 64; ++o) {
    float a = 0.f;
#pragma unroll
    for (int c = 0; c < C_; ++c) a = fmaf(cent[c], w1[o * 80 + c], a);
    base[o] = a;
  }

#pragma unroll 1
  for (int kk = 0; kk < 6; ++kk) {
    float neigh[C_];
    {
      const float4* np = (const float4*)(xt + ((size_t)((b << 11) + mk[kk])) * C_);
#pragma unroll
      for (int q = 0; q < 8; ++q) {
        float4 v = np[q];
        neigh[4*q] = v.x; neigh[4*q+1] = v.y; neigh[4*q+2] = v.z; neigh[4*q+3] = v.w;
      }
    }
    float dist = sqrtf(fmaxf(dd[kk], 1e-12f));
    float rbf[16];
#pragma unroll
    for (int r = 0; r < 16; ++r) {
      float t = dist - (float)r * (5.0f / 15.0f);
      float e = __expf(-10.f * t * t);
      rbf[r] = fminf(fmaxf(e, 1e-10f), 1.0f);
    }
    float lg = 0.f;
#pragma unroll 2
    for (int o = 0; o < 64; ++o) {
      float acc = base[o];
#pragma unroll
      for (int c = 0; c < C_; ++c) acc = fmaf(neigh[c], w1[o * 80 + 32 + c], acc);
#pragma unroll
      for (int r = 0; r < 16; ++r)  acc = fmaf(rbf[r], w1[o * 80 + 64 + r], acc);
      float h = acc > 0.f ? acc : 0.2f * acc;   /* leaky 0.2 */
      lg = fmaf(h, w2[o], lg);
    }
    lgs[lane][wv * 6 + kk] = lg;
  }
  __syncthreads();
  if (wv == 0) {
    float l[K_];
#pragma unroll
    for (int k = 0; k < K_; ++k) l[k] = lgs[lane][k];
    float mx = l[0];
#pragma unroll
    for (int k = 1; k < K_; ++k) mx = fmaxf(mx, l[k]);
    float den = 0.f;
#pragma unroll
    for (int k = 0; k < K_; ++k) { l[k] = __expf(l[k] - mx); den += l[k]; }
    const float inv = 1.f / den;
    float* ap = ws + WS_ATT + (size_t)bn * K_;
#pragma unroll
    for (int k = 0; k < K_; ++k) ap[k] = l[k] * inv;
  }
}

/* ---------------- K2b: BN statistics (lane = point, wave = o-slice) ------- */
__global__ __launch_bounds__(256, 2) void k2b_stats(const float* __restrict__ updw,
                                                    float* __restrict__ ws) {
  const int lane = threadIdx.x & 63;
  const int wv   = __builtin_amdgcn_readfirstlane(threadIdx.x >> 6);
  const int o0   = wv * 16;
  const int bn   = blockIdx.x * 64 + lane;
  const int b    = bn >> 11;
  const float* xt = ws + WS_XT;

  int   mk[K_];
  float at[K_];
  {
    const int4*   ip = (const int4*)((const int*)ws + WS_IDX + (size_t)bn * K_);
    const float4* ap = (const float4*)(ws + WS_ATT + (size_t)bn * K_);
#pragma unroll
    for (int q = 0; q < 6; ++q) {
      int4  iv = ip[q];
      float4 av = ap[q];
      mk[4*q] = iv.x; mk[4*q+1] = iv.y; mk[4*q+2] = iv.z; mk[4*q+3] = iv.w;
      at[4*q] = av.x; at[4*q+1] = av.y; at[4*q+2] = av.z; at[4*q+3] = av.w;
    }
  }

  float s1[16], s2[16];
#pragma unroll
  for (int oo = 0; oo < 16; ++oo) { s1[oo] = 0.f; s2[oo] = 0.f; }

#pragma unroll 1
  for (int k = 0; k < K_; ++k) {
    float row[C_];
    {
      const float4* np = (const float4*)(xt + ((size_t)((b << 11) + mk[k])) * C_);
#pragma unroll
      for (int q = 0; q < 8; ++q) {
        float4 v = np[q];
        row[4*q] = v.x; row[4*q+1] = v.y; row[4*q+2] = v.z; row[4*q+3] = v.w;
      }
    }
#pragma unroll
    for (int oo = 0; oo < 16; ++oo) {
      const float* wr = updw + (o0 + oo) * C_;   /* wave-uniform -> s_load */
      float na = 0.f;
#pragma unroll
      for (int c = 0; c < C_; ++c) na = fmaf(row[c], wr[c], na);
      float u = at[k] * na;
      s1[oo] += u;
      s2[oo] = fmaf(u, u, s2[oo]);
    }
  }
  /* butterfly reduce across 64 lanes, then lane0 atomics */
#pragma unroll
  for (int oo = 0; oo < 16; ++oo) {
#pragma unroll
    for (int d = 1; d < 64; d <<= 1) {
      s1[oo] += __shfl_xor(s1[oo], d, 64);
      s2[oo] += __shfl_xor(s2[oo], d, 64);
    }
  }
  if (lane == 0) {
#pragma unroll
    for (int oo = 0; oo < 16; ++oo) {
      atomicAdd(ws + WS_ST + o0 + oo, s1[oo]);
      atomicAdd(ws + WS_ST + 64 + o0 + oo, s2[oo]);
    }
  }
}

/* ---------------- K3: finalize BN scale/shift ----------------------------- */
__global__ void k3_bn(const float* __restrict__ gam, const float* __restrict__ bet,
                      float* __restrict__ ws) {
  const int o = threadIdx.x;   /* 64 */
  float s1 = ws[WS_ST + o], s2 = ws[WS_ST + 64 + o];
  const float cnt = (float)BNK_;
  float mean = s1 / cnt;
  float var = fmaxf(s2 / cnt - mean * mean, 0.f);
  float A = gam[o] / sqrtf(var + 1e-5f);
  ws[WS_AB + o] = A;
  ws[WS_AB + 64 + o] = bet[o] - mean * A;
}

/* ---------------- K4: BN apply + leaky + residual + mean_k + store -------- */
__global__ __launch_bounds__(256, 2) void k4_out(const float* __restrict__ updw,
                                                 const float* __restrict__ resw,
                                                 float* __restrict__ out,
                                                 const float* __restrict__ ws) {
  const int lane = threadIdx.x & 63;                 /* = point            */
  const int wv   = __builtin_amdgcn_readfirstlane(threadIdx.x >> 6);
  const int o0   = wv * 16;                          /* o-slice            */
  const int bn   = blockIdx.x * 64 + lane;
  const int b    = bn >> 11, n = bn & 2047;
  const float* xt = ws + WS_XT;

  int   mk[K_];
  float at[K_];
  {
    const int4*   ip = (const int4*)((const int*)ws + WS_IDX + (size_t)bn * K_);
    const float4* ap = (const float4*)(ws + WS_ATT + (size_t)bn * K_);
#pragma unroll
    for (int q = 0; q < 6; ++q) {
      int4  iv = ip[q];
      float4 av = ap[q];
      mk[4*q] = iv.x; mk[4*q+1] = iv.y; mk[4*q+2] = iv.z; mk[4*q+3] = iv.w;
      at[4*q] = av.x; at[4*q+1] = av.y; at[4*q+2] = av.z; at[4*q+3] = av.w;
    }
  }

  float facc[16], racc[16];
#pragma unroll
  for (int oo = 0; oo < 16; ++oo) { facc[oo] = 0.f; racc[oo] = 0.f; }

#pragma unroll 1
  for (int k = 0; k < K_; ++k) {
    float row[C_];
    {
      const float4* np = (const float4*)(xt + ((size_t)((b << 11) + mk[k])) * C_);
#pragma unroll
      for (int q = 0; q < 8; ++q) {
        float4 v = np[q];
        row[4*q] = v.x; row[4*q+1] = v.y; row[4*q+2] = v.z; row[4*q+3] = v.w;
      }
    }
#pragma unroll
    for (int oo = 0; oo < 16; ++oo) {
      const float* wu = updw + (o0 + oo) * C_;   /* wave-uniform */
      const float* wr = resw + (o0 + oo) * C_;
      float na = 0.f, ra = 0.f;
#pragma unroll
      for (int c = 0; c < C_; ++c) {
        na = fmaf(row[c], wu[c], na);
        ra = fmaf(row[c], wr[c], ra);
      }
      float u = at[k] * na;
      float v = fmaf(u, ws[WS_AB + o0 + oo], ws[WS_AB + 64 + o0 + oo]);
      v = v > 0.f ? v : 0.02f * v;    /* leaky 0.02 */
      facc[oo] += v;
      racc[oo] += ra;
    }
  }
#pragma unroll
  for (int oo = 0; oo < 16; ++oo)
    out[((size_t)(b * 64 + o0 + oo)) * N_ + n] = (facc[oo] + 0.1f * racc[oo]) * (1.f / 24.f);
}

extern "C" void kernel_launch(void* const* d_in, const int* in_sizes, int n_in,
                              void* d_out, int out_size, void* d_ws, size_t ws_size,
                              hipStream_t stream) {
  (void)in_sizes; (void)n_in; (void)out_size; (void)ws_size;
  const float* x    = (const float*)d_in[0];
  /* d_in[1] = idx_base (unused by reference) */
  const float* w1   = (const float*)d_in[2];
  const float* w2   = (const float*)d_in[3];
  const float* updw = (const float*)d_in[4];
  const float* bng  = (const float*)d_in[5];
  const float* bnb  = (const float*)d_in[6];
  const float* resw = (const float*)d_in[7];
  float* out = (float*)d_out;
  float* ws  = (float*)d_ws;

  k0_prep  <<<dim3(128), dim3(256), 0, stream>>>(x, ws);
  k1_topk  <<<dim3(512), dim3(256), 0, stream>>>(ws);
  k2a_att  <<<dim3(512), dim3(256), 0, stream>>>(w1, w2, ws);
  k2b_stats<<<dim3(512), dim3(256), 0, stream>>>(updw, ws);
  k3_bn    <<<dim3(1),   dim3(64),  0, stream>>>(bng, bnb, ws);
  k4_out   <<<dim3(512), dim3(256), 0, stream>>>(updw, resw, out, ws);
}

// Round 5
// 693.568 us; speedup vs baseline: 1.3877x; 1.3877x over previous
//
#include <hip/hip_runtime.h>
#include <math.h>

#define B_   16
#define C_   32
#define N_   2048
#define K_   24
#define BNK_ (B_*N_*K_)      /* 786432 */

/* ws layout (float/int32 units), ~30.8 MB total */
#define WS_XT   0u           /* xt[b][n][c]  : 1048576 f            */
#define WS_XXD  1048576u     /* xx[b][n] fp64: 32768 d = 65536 f    */
#define WS_XXF  1114112u     /* xx[b][n] fp32: 32768 f              */
#define WS_IDX  1146880u     /* idx[b][n][k] : 786432 i             */
#define WS_D2   1933312u     /* d2 [b][n][k] : 786432 f             */
#define WS_ATT  2719744u     /* att[b][n][k] : 786432 f             */
#define WS_ST   3506176u     /* sum/sumsq    : 128 f                */
#define WS_AB   3506304u     /* BN A,B       : 128 f                */
#define WS_Y    3506432u     /* Y[m][128]    : 4194304 f (att|upd)  */

/* ---------------- K0: transpose x -> xt, row norms (fp64+fp32), zero stats */
__global__ __launch_bounds__(256) void k0_prep(const float* __restrict__ x,
                                               float* __restrict__ ws) {
  int t = blockIdx.x * 256 + threadIdx.x;     /* 0..32767 = b*2048+n */
  int b = t >> 11, n = t & 2047;
  const float* xp = x + ((size_t)b * C_ * N_) + n;
  float* xt = ws + WS_XT + (size_t)t * C_;
  double s = 0.0;
#pragma unroll
  for (int c = 0; c < C_; ++c) {
    float v = xp[(size_t)c * N_];
    xt[c] = v;
    s = fma((double)v, (double)v, s);
  }
  ((double*)(ws + WS_XXD))[t] = s;
  ws[WS_XXF + t] = (float)s;
  if (t < 128) ws[WS_ST + t] = 0.f;
}

/* ---------------- K1: exact top-24 neighbors per (b,n) --------------------
   fp32 scan + med3 insert, fp64 re-rank of 24 survivors, 4-way merge.     */
__global__ __launch_bounds__(256, 2) void k1_topk(float* __restrict__ ws) {
  __shared__ double pv[4][64][25];
  const float* xt = ws + WS_XT;
  const double* xxd = (const double*)(ws + WS_XXD);
  const int lane = threadIdx.x & 63;
  const int wv   = __builtin_amdgcn_readfirstlane(threadIdx.x >> 6);
  const int g = blockIdx.x;          /* 0..511 */
  const int b = g >> 5;
  const int n = ((g & 31) << 6) + lane;
  const int bn = (b << 11) + n;

  float xn[C_];
  {
    const float4* p = (const float4*)(xt + (size_t)bn * C_);
#pragma unroll
    for (int q = 0; q < 8; ++q) {
      float4 v = p[q];
      xn[4*q] = v.x; xn[4*q+1] = v.y; xn[4*q+2] = v.z; xn[4*q+3] = v.w;
    }
  }

  float val[K_];
#pragma unroll
  for (int j = 0; j < K_; ++j) val[j] = -3.4e38f;

  const float* mrow = xt + ((size_t)((b << 11) + (wv << 9))) * C_;  /* uniform */
  const float* xxf  = ws + WS_XXF + (b << 11) + (wv << 9);          /* uniform */

#pragma unroll 2
  for (int mm = 0; mm < 512; ++mm) {
    const float* r = mrow + (size_t)mm * C_;   /* wave-uniform -> s_load */
    float a0 = 0.f, a1 = 0.f, a2 = 0.f, a3 = 0.f;
#pragma unroll
    for (int c = 0; c < 8; ++c) {
      a0 = fmaf(xn[c     ], r[c     ], a0);
      a1 = fmaf(xn[c + 8 ], r[c + 8 ], a1);
      a2 = fmaf(xn[c + 16], r[c + 16], a2);
      a3 = fmaf(xn[c + 24], r[c + 24], a3);
    }
    float s = 2.f * ((a0 + a1) + (a2 + a3)) - xxf[mm];
    int sb = (__float_as_int(s) & ~2047) | ((wv << 9) + mm);
    float sp = __int_as_float(sb);
#pragma unroll
    for (int j = K_ - 1; j >= 1; --j)
      val[j] = __builtin_amdgcn_fmed3f(val[j - 1], val[j], sp);
    val[0] = fmaxf(val[0], sp);
  }

  /* fp64 re-rank of this wave's 24 candidates */
  double xnd[C_];
#pragma unroll
  for (int c = 0; c < C_; ++c) xnd[c] = (double)xn[c];

  double dl[K_];
#pragma unroll
  for (int j = 0; j < K_; ++j) dl[j] = -1.7e308;

#pragma unroll 1
  for (int j = 0; j < K_; ++j) {
    const int m = __float_as_int(val[j]) & 2047;
    const float* r = xt + ((size_t)((b << 11) + m)) * C_;
    double a0 = 0.0, a1 = 0.0;
#pragma unroll
    for (int c = 0; c < 16; ++c) {
      a0 = fma((double)r[c],      xnd[c],      a0);
      a1 = fma((double)r[c + 16], xnd[c + 16], a1);
    }
    double s = 2.0 * (a0 + a1) - xxd[(b << 11) + m];
    long long bits = (__double_as_longlong(s) & 0xFFFFFFFFFFFFF800ll) | (long long)m;
    double sp = __longlong_as_double(bits);
    bool c2 = true;
#pragma unroll
    for (int jj = K_ - 1; jj >= 1; --jj) {
      bool c1 = sp > dl[jj - 1];
      dl[jj] = c1 ? dl[jj - 1] : (c2 ? sp : dl[jj]);
      c2 = c1;
    }
    if (c2) dl[0] = sp;
  }
#pragma unroll
  for (int j = 0; j < K_; ++j) pv[wv][lane][j] = dl[j];
  pv[wv][lane][K_] = -1.7e308;
  __syncthreads();

  if (wv == 0) {
    int i0 = 0, i1 = 0, i2 = 0, i3 = 0;
    double v0 = pv[0][lane][0], v1 = pv[1][lane][0], v2 = pv[2][lane][0], v3 = pv[3][lane][0];
    int*   op = (int*)ws + WS_IDX + (size_t)bn * K_;
    float* dp = ws + WS_D2 + (size_t)bn * K_;
    const double xxn = xxd[bn];
#pragma unroll 1
    for (int rr = 0; rr < K_; ++rr) {
      double bv = v0; int bq = 0;
      if (v1 > bv) { bv = v1; bq = 1; }
      if (v2 > bv) { bv = v2; bq = 2; }
      if (v3 > bv) { bv = v3; bq = 3; }
      long long bl = __double_as_longlong(bv);
      op[rr] = (int)(bl & 0x7FFll);
      dp[rr] = (float)(xxn - __longlong_as_double(bl & 0xFFFFFFFFFFFFF800ll));
      if      (bq == 0) { ++i0; v0 = pv[0][lane][i0]; }
      else if (bq == 1) { ++i1; v1 = pv[1][lane][i1]; }
      else if (bq == 2) { ++i2; v2 = pv[2][lane][i2]; }
      else              { ++i3; v3 = pv[3][lane][i3]; }
    }
  }
}

/* ---------------- KY: per-point GEMM  Y[m] = [xt[m]·w1n^T | xt[m]·updw^T] - */
/* 256 blocks x 256. Waves 0,1 of a block: h=0 (y_att); waves 2,3: h=1
   (y_upd). Each thread computes 64 channels for one point.                */
__global__ __launch_bounds__(256) void kY(const float* __restrict__ w1,
                                          const float* __restrict__ updw,
                                          float* __restrict__ ws) {
  const int t = threadIdx.x;
  const int h = __builtin_amdgcn_readfirstlane(t >> 7);   /* wave-uniform */
  const int p = blockIdx.x * 128 + (t & 127);
  const float* xt = ws + WS_XT;

  float row[C_];
  {
    const float4* rp = (const float4*)(xt + (size_t)p * C_);
#pragma unroll
    for (int q = 0; q < 8; ++q) {
      float4 v = rp[q];
      row[4*q] = v.x; row[4*q+1] = v.y; row[4*q+2] = v.z; row[4*q+3] = v.w;
    }
  }
  const float* W   = h ? updw : (w1 + 32);   /* wave-uniform base */
  const int stride = h ? 32 : 80;
  float* yp = ws + WS_Y + (size_t)p * 128 + h * 64;
#pragma unroll 2
  for (int og = 0; og < 16; ++og) {
    float a[4] = {0.f, 0.f, 0.f, 0.f};
#pragma unroll
    for (int u = 0; u < 4; ++u) {
      const float* wr = W + (4 * og + u) * stride;   /* uniform -> s_load */
#pragma unroll
      for (int c = 0; c < C_; ++c) a[u] = fmaf(row[c], wr[c], a[u]);
    }
    float4 st; st.x = a[0]; st.y = a[1]; st.z = a[2]; st.w = a[3];
    ((float4*)yp)[og] = st;
  }
}

/* ---------------- K2a: attention MLP + softmax (lane = point) -------------
   Per k: gather y_att row (neigh·w1n precomputed); only the RBF·w1r part
   (16 fma/o) remains per-(bn,k,o).                                        */
__global__ __launch_bounds__(256, 2) void k2a_att(const float* __restrict__ w1,
                                                  const float* __restrict__ w2,
                                                  float* __restrict__ ws) {
  __shared__ float lgs[64][25];
  const int lane = threadIdx.x & 63;
  const int wv   = threadIdx.x >> 6;
  const int bn   = blockIdx.x * 64 + lane;
  const int b    = bn >> 11;
  const float* xt = ws + WS_XT;
  const float* Y  = ws + WS_Y;

  int   mk[6];
  float dd[6];
  {
    const int*   ip = (const int*)ws + WS_IDX + (size_t)bn * K_;
    const float* dp = ws + WS_D2 + (size_t)bn * K_;
#pragma unroll
    for (int kk = 0; kk < 6; ++kk) { mk[kk] = ip[wv * 6 + kk]; dd[kk] = dp[wv * 6 + kk]; }
  }

  /* base[o] = cent · w1[o][0:32]  (once per point, w1 uniform s_load) */
  float base[64];
  {
    float cent[C_];
    const float4* cp = (const float4*)(xt + (size_t)bn * C_);
#pragma unroll
    for (int q = 0; q < 8; ++q) {
      float4 v = cp[q];
      cent[4*q] = v.x; cent[4*q+1] = v.y; cent[4*q+2] = v.z; cent[4*q+3] = v.w;
    }
#pragma unroll 4
    for (int o = 0; o < 64; ++o) {
      float a = 0.f;
#pragma unroll
      for (int c = 0; c < C_; ++c) a = fmaf(cent[c], w1[o * 80 + c], a);
      base[o] = a;
    }
  }

#pragma unroll 1
  for (int kk = 0; kk < 6; ++kk) {
    float row[64];
    {
      const float4* yp = (const float4*)(Y + (size_t)((b << 11) + mk[kk]) * 128);
#pragma unroll
      for (int q = 0; q < 16; ++q) {
        float4 v = yp[q];
        row[4*q] = v.x; row[4*q+1] = v.y; row[4*q+2] = v.z; row[4*q+3] = v.w;
      }
    }
    float dist = sqrtf(fmaxf(dd[kk], 1e-12f));
    float rbf[16];
#pragma unroll
    for (int r = 0; r < 16; ++r) {
      float t = dist - (float)r * (5.0f / 15.0f);
      float e = __expf(-10.f * t * t);
      rbf[r] = fminf(fmaxf(e, 1e-10f), 1.0f);
    }
    float lg = 0.f;
#pragma unroll 2
    for (int o = 0; o < 64; ++o) {
      float acc = base[o] + row[o];
#pragma unroll
      for (int r = 0; r < 16; ++r) acc = fmaf(rbf[r], w1[o * 80 + 64 + r], acc);
      float h = acc > 0.f ? acc : 0.2f * acc;   /* leaky 0.2 */
      lg = fmaf(h, w2[o], lg);
    }
    lgs[lane][wv * 6 + kk] = lg;
  }
  __syncthreads();
  if (wv == 0) {
    float l[K_];
#pragma unroll
    for (int k = 0; k < K_; ++k) l[k] = lgs[lane][k];
    float mx = l[0];
#pragma unroll
    for (int k = 1; k < K_; ++k) mx = fmaxf(mx, l[k]);
    float den = 0.f;
#pragma unroll
    for (int k = 0; k < K_; ++k) { l[k] = __expf(l[k] - mx); den += l[k]; }
    const float inv = 1.f / den;
    float* ap = ws + WS_ATT + (size_t)bn * K_;
#pragma unroll
    for (int k = 0; k < K_; ++k) ap[k] = l[k] * inv;
  }
}

/* ---------------- K2b: BN statistics (wave = point, lane = channel) ------- */
__global__ __launch_bounds__(256, 2) void k2b_stats(float* __restrict__ ws) {
  __shared__ float ls[128];
  const int lane = threadIdx.x & 63;
  const int wv   = __builtin_amdgcn_readfirstlane(threadIdx.x >> 6);
  if (threadIdx.x < 128) ls[threadIdx.x] = 0.f;
  __syncthreads();
  const int w = blockIdx.x * 4 + wv;
  const float* Y = ws + WS_Y;
  float s1 = 0.f, s2 = 0.f;
#pragma unroll 1
  for (int i = 0; i < 16; ++i) {
    const int bn = w * 16 + i;                  /* wave-uniform */
    const int b  = bn >> 11;
    const int*   ip = (const int*)ws + WS_IDX + (size_t)bn * K_;   /* s_load */
    const float* ap = ws + WS_ATT + (size_t)bn * K_;               /* s_load */
#pragma unroll
    for (int k = 0; k < K_; ++k) {
      const int mk = ip[k];
      float yv = Y[(size_t)((b << 11) + mk) * 128 + 64 + lane];    /* coalesced */
      float u = ap[k] * yv;
      s1 += u;
      s2 = fmaf(u, u, s2);
    }
  }
  atomicAdd(&ls[lane], s1);
  atomicAdd(&ls[64 + lane], s2);
  __syncthreads();
  if (threadIdx.x < 128) atomicAdd(ws + WS_ST + threadIdx.x, ls[threadIdx.x]);
}

/* ---------------- K3: finalize BN scale/shift ----------------------------- */
__global__ void k3_bn(const float* __restrict__ gam, const float* __restrict__ bet,
                      float* __restrict__ ws) {
  const int o = threadIdx.x;   /* 64 */
  float s1 = ws[WS_ST + o], s2 = ws[WS_ST + 64 + o];
  const float cnt = (float)BNK_;
  float mean = s1 / cnt;
  float var = fmaxf(s2 / cnt - mean * mean, 0.f);
  float A = gam[o] / sqrtf(var + 1e-5f);
  ws[WS_AB + o] = A;
  ws[WS_AB + 64 + o] = bet[o] - mean * A;
}

/* ---------------- K4: BN apply + leaky + residual + mean_k + store --------
   wave = point, lane = output channel. upd via Y gathers (coalesced);
   residual via linearity: sum xt rows, one shuffle-broadcast dot.         */
__global__ __launch_bounds__(256, 2) void k4_out(const float* __restrict__ resw,
                                                 float* __restrict__ out,
                                                 const float* __restrict__ ws) {
  const int lane = threadIdx.x & 63;
  const int wv   = __builtin_amdgcn_readfirstlane(threadIdx.x >> 6);
  const int w = blockIdx.x * 4 + wv;
  const float* Y  = ws + WS_Y;
  const float* xt = ws + WS_XT;

  float rw[C_];
  {
    const float4* rp = (const float4*)(resw + lane * C_);
#pragma unroll
    for (int q = 0; q < 8; ++q) {
      float4 v = rp[q];
      rw[4*q] = v.x; rw[4*q+1] = v.y; rw[4*q+2] = v.z; rw[4*q+3] = v.w;
    }
  }
  const float A  = ws[WS_AB + lane];
  const float Bb = ws[WS_AB + 64 + lane];
  const int c  = lane & 31;
  const int kh = lane >> 5;

#pragma unroll 1
  for (int i = 0; i < 16; ++i) {
    const int bn = w * 16 + i;                  /* wave-uniform */
    const int b = bn >> 11, n = bn & 2047;
    const int*   ip = (const int*)ws + WS_IDX + (size_t)bn * K_;   /* s_load */
    const float* ap = ws + WS_ATT + (size_t)bn * K_;               /* s_load */

    float facc = 0.f;
#pragma unroll
    for (int k = 0; k < K_; ++k) {
      const int mk = ip[k];
      float yv = Y[(size_t)((b << 11) + mk) * 128 + 64 + lane];    /* coalesced */
      float u = ap[k] * yv;
      float v = fmaf(u, A, Bb);
      v = v > 0.f ? v : 0.02f * v;    /* leaky 0.02 */
      facc += v;
    }
    /* residual: sx(lane) = sum over k of parity kh of xt[mk][c] */
    float sx = 0.f;
#pragma unroll
    for (int kp = 0; kp < 12; ++kp) {
      const int mk = ip[2 * kp + kh];
      sx += xt[(size_t)((b << 11) + mk) * C_ + c];
    }
    float racc = 0.f;
#pragma unroll
    for (int cc = 0; cc < 64; ++cc)
      racc = fmaf(__shfl(sx, cc, 64), rw[cc & 31], racc);

    out[((size_t)(b * 64 + lane)) * N_ + n] = (facc + 0.1f * racc) * (1.f / 24.f);
  }
}

extern "C" void kernel_launch(void* const* d_in, const int* in_sizes, int n_in,
                              void* d_out, int out_size, void* d_ws, size_t ws_size,
                              hipStream_t stream) {
  (void)in_sizes; (void)n_in; (void)out_size; (void)ws_size;
  const float* x    = (const float*)d_in[0];
  /* d_in[1] = idx_base (unused by reference) */
  const float* w1   = (const float*)d_in[2];
  const float* w2   = (const float*)d_in[3];
  const float* updw = (const float*)d_in[4];
  const float* bng  = (const float*)d_in[5];
  const float* bnb  = (const float*)d_in[6];
  const float* resw = (const float*)d_in[7];
  float* out = (float*)d_out;
  float* ws  = (float*)d_ws;

  k0_prep  <<<dim3(128), dim3(256), 0, stream>>>(x, ws);
  k1_topk  <<<dim3(512), dim3(256), 0, stream>>>(ws);
  kY       <<<dim3(256), dim3(256), 0, stream>>>(w1, updw, ws);
  k2a_att  <<<dim3(512), dim3(256), 0, stream>>>(w1, w2, ws);
  k2b_stats<<<dim3(512), dim3(256), 0, stream>>>(ws);
  k3_bn    <<<dim3(1),   dim3(64),  0, stream>>>(bng, bnb, ws);
  k4_out   <<<dim3(512), dim3(256), 0, stream>>>(resw, out, ws);
}

// Round 7
// 666.624 us; speedup vs baseline: 1.4438x; 1.0404x over previous
//
#include <hip/hip_runtime.h>
#include <math.h>

#define B_   16
#define C_   32
#define N_   2048
#define K_   24
#define BNK_ (B_*N_*K_)      /* 786432 */

/* ws layout (float/int32 units), ~56 MB total */
#define WS_XT   0u           /* xt[b][n][c]  : 1048576 f            */
#define WS_XXD  1048576u     /* xx[b][n] fp64: 32768 d = 65536 f    */
#define WS_XXF  1114112u     /* xx[b][n] fp32: 32768 f              */
#define WS_IDX  1146880u     /* idx[b][n][k] : 786432 i             */
#define WS_D2   1933312u     /* d2 [b][n][k] : 786432 f             */
#define WS_ATT  2719744u     /* att[b][n][k] : 786432 f             */
#define WS_ST   3506176u     /* sum/sumsq    : 128 f                */
#define WS_AB   3506304u     /* BN A,B       : 128 f                */
#define WS_Y    3506432u     /* Y[m][128]    : 4194304 f (att|upd)  */
#define WS_L    7700736u     /* lists[pg][e][j][lane] : 6291456 f   */

/* ---------------- K0: transpose x -> xt, row norms (fp64+fp32), zero stats */
__global__ __launch_bounds__(256) void k0_prep(const float* __restrict__ x,
                                               float* __restrict__ ws) {
  int t = blockIdx.x * 256 + threadIdx.x;     /* 0..32767 = b*2048+n */
  int b = t >> 11, n = t & 2047;
  const float* xp = x + ((size_t)b * C_ * N_) + n;
  float* xt = ws + WS_XT + (size_t)t * C_;
  double s = 0.0;
#pragma unroll
  for (int c = 0; c < C_; ++c) {
    float v = xp[(size_t)c * N_];
    xt[c] = v;
    s = fma((double)v, (double)v, s);
  }
  ((double*)(ws + WS_XXD))[t] = s;
  ws[WS_XXF + t] = (float)s;
  if (t < 128) ws[WS_ST + t] = 0.f;
}

/* ---------------- K1a: fp32 scan of one m-eighth per wave -----------------
   4096 independent waves (1024 blocks x 4), zero LDS. Per wave: 64 points
   (lanes) x 256 candidates; med3 insertion top-24 (med3 form is correct
   for arbitrary insert counts); 11-bit global m packed in fp32 mantissa
   low bits. Sorted list written coalesced to ws[pg][e][j][lane].          */
__global__ __launch_bounds__(256) void k1a_scan(float* __restrict__ ws) {
  const float* xt = ws + WS_XT;
  const int lane = threadIdx.x & 63;
  const int wv   = __builtin_amdgcn_readfirstlane(threadIdx.x >> 6);
  const int pg   = blockIdx.x >> 1;                      /* 0..511 */
  const int e    = ((blockIdx.x & 1) << 2) | wv;         /* 0..7   */
  const int b = pg >> 5;
  const int n = ((pg & 31) << 6) + lane;
  const int bn = (b << 11) + n;

  float xn[C_];
  {
    const float4* p = (const float4*)(xt + (size_t)bn * C_);
#pragma unroll
    for (int q = 0; q < 8; ++q) {
      float4 v = p[q];
      xn[4*q] = v.x; xn[4*q+1] = v.y; xn[4*q+2] = v.z; xn[4*q+3] = v.w;
    }
  }

  float val[K_];
#pragma unroll
  for (int j = 0; j < K_; ++j) val[j] = -3.4e38f;

  const float* mrow = xt + ((size_t)((b << 11) + (e << 8))) * C_;  /* uniform */
  const float* xxf  = ws + WS_XXF + (b << 11) + (e << 8);          /* uniform */

#pragma unroll 2
  for (int mm = 0; mm < 256; ++mm) {
    const float* r = mrow + (size_t)mm * C_;   /* wave-uniform -> s_load */
    float a0 = 0.f, a1 = 0.f, a2 = 0.f, a3 = 0.f;
#pragma unroll
    for (int c = 0; c < 8; ++c) {
      a0 = fmaf(xn[c     ], r[c     ], a0);
      a1 = fmaf(xn[c + 8 ], r[c + 8 ], a1);
      a2 = fmaf(xn[c + 16], r[c + 16], a2);
      a3 = fmaf(xn[c + 24], r[c + 24], a3);
    }
    float s = 2.f * ((a0 + a1) + (a2 + a3)) - xxf[mm];
    int sb = (__float_as_int(s) & ~2047) | ((e << 8) + mm);
    float sp = __int_as_float(sb);
#pragma unroll
    for (int j = K_ - 1; j >= 1; --j)
      val[j] = __builtin_amdgcn_fmed3f(val[j - 1], val[j], sp);
    val[0] = fmaxf(val[0], sp);
  }

  float* Lp = ws + WS_L + (((size_t)pg * 8 + e) * K_) * 64 + lane;
#pragma unroll
  for (int j = 0; j < K_; ++j) Lp[(size_t)j * 64] = val[j];   /* coalesced */
}

/* ---------------- K1b: union select + exact fp64 re-rank ------------------
   One wave per point-group (512 blocks x 64 thr). Per lane: stream the
   192-entry union (coalesced), med3-select fp32 top-32 (8-deep slack at
   the cut), fp64 re-rank those 32 exactly (GUARDED insert — the round-6
   bug was inserting 32 values into a 24-list whose branchless insert
   assumed sp > dl[23]), emit top-24 idx + d2.                             */
__global__ __launch_bounds__(64) void k1b_sel(float* __restrict__ ws) {
  const float* xt = ws + WS_XT;
  const double* xxd = (const double*)(ws + WS_XXD);
  const int lane = threadIdx.x & 63;
  const int pg   = blockIdx.x;             /* 0..511 */
  const int b = pg >> 5;
  const int n = ((pg & 31) << 6) + lane;
  const int bn = (b << 11) + n;

  /* fp32 select of top-32 from the 192-entry union (streaming, coalesced) */
  float val[32];
#pragma unroll
  for (int j = 0; j < 32; ++j) val[j] = -3.4e38f;
  const float* Lp = ws + WS_L + ((size_t)pg * 8 * K_) * 64 + lane;
#pragma unroll 4
  for (int t = 0; t < 192; ++t) {
    float sp = Lp[(size_t)t * 64];
#pragma unroll
    for (int j = 31; j >= 1; --j)
      val[j] = __builtin_amdgcn_fmed3f(val[j - 1], val[j], sp);
    val[0] = fmaxf(val[0], sp);
  }

  /* fp64 re-rank of the 32 survivors */
  double xnd[C_];
  {
    const float* p = xt + (size_t)bn * C_;
#pragma unroll
    for (int c = 0; c < C_; ++c) xnd[c] = (double)p[c];
  }
  double dl[K_];
#pragma unroll
  for (int j = 0; j < K_; ++j) dl[j] = -1.7e308;

#pragma unroll 1
  for (int j = 0; j < 32; ++j) {
    const int m = __float_as_int(val[j]) & 2047;
    const float* r = xt + ((size_t)((b << 11) + m)) * C_;
    double a0 = 0.0, a1 = 0.0;
#pragma unroll
    for (int c = 0; c < 16; ++c) {
      a0 = fma((double)r[c],      xnd[c],      a0);
      a1 = fma((double)r[c + 16], xnd[c + 16], a1);
    }
    double s = 2.0 * (a0 + a1) - xxd[(b << 11) + m];
    long long bits = (__double_as_longlong(s) & 0xFFFFFFFFFFFFF800ll) | (long long)m;
    double sp = __longlong_as_double(bits);
    if (sp > dl[K_ - 1]) {     /* guard: insert only if it beats the floor */
      bool c2 = true;
#pragma unroll
      for (int jj = K_ - 1; jj >= 1; --jj) {
        bool c1 = sp > dl[jj - 1];
        dl[jj] = c1 ? dl[jj - 1] : (c2 ? sp : dl[jj]);
        c2 = c1;
      }
      if (c2) dl[0] = sp;
    }
  }

  int*   op = (int*)ws + WS_IDX + (size_t)bn * K_;
  float* dp = ws + WS_D2 + (size_t)bn * K_;
  const double xxn = xxd[bn];
#pragma unroll
  for (int rr = 0; rr < K_; ++rr) {
    long long bl = __double_as_longlong(dl[rr]);
    op[rr] = (int)(bl & 0x7FFll);
    dp[rr] = (float)(xxn - __longlong_as_double(bl & 0xFFFFFFFFFFFFF800ll));
  }
}

/* ---------------- KY: per-point GEMM  Y[m] = [xt[m]·w1n^T | xt[m]·updw^T] - */
__global__ __launch_bounds__(256) void kY(const float* __restrict__ w1,
                                          const float* __restrict__ updw,
                                          float* __restrict__ ws) {
  const int t = threadIdx.x;
  const int h = __builtin_amdgcn_readfirstlane(t >> 7);   /* wave-uniform */
  const int p = blockIdx.x * 128 + (t & 127);
  const float* xt = ws + WS_XT;

  float row[C_];
  {
    const float4* rp = (const float4*)(xt + (size_t)p * C_);
#pragma unroll
    for (int q = 0; q < 8; ++q) {
      float4 v = rp[q];
      row[4*q] = v.x; row[4*q+1] = v.y; row[4*q+2] = v.z; row[4*q+3] = v.w;
    }
  }
  const float* W   = h ? updw : (w1 + 32);   /* wave-uniform base */
  const int stride = h ? 32 : 80;
  float* yp = ws + WS_Y + (size_t)p * 128 + h * 64;
#pragma unroll 2
  for (int og = 0; og < 16; ++og) {
    float a[4] = {0.f, 0.f, 0.f, 0.f};
#pragma unroll
    for (int u = 0; u < 4; ++u) {
      const float* wr = W + (4 * og + u) * stride;   /* uniform -> s_load */
#pragma unroll
      for (int c = 0; c < C_; ++c) a[u] = fmaf(row[c], wr[c], a[u]);
    }
    float4 st; st.x = a[0]; st.y = a[1]; st.z = a[2]; st.w = a[3];
    ((float4*)yp)[og] = st;
  }
}

/* ---------------- K2a: attention MLP + softmax (lane = point) ------------- */
__global__ __launch_bounds__(256, 2) void k2a_att(const float* __restrict__ w1,
                                                  const float* __restrict__ w2,
                                                  float* __restrict__ ws) {
  __shared__ float lgs[64][25];
  const int lane = threadIdx.x & 63;
  const int wv   = threadIdx.x >> 6;
  const int bn   = blockIdx.x * 64 + lane;
  const int b    = bn >> 11;
  const float* xt = ws + WS_XT;
  const float* Y  = ws + WS_Y;

  int   mk[6];
  float dd[6];
  {
    const int*   ip = (const int*)ws + WS_IDX + (size_t)bn * K_;
    const float* dp = ws + WS_D2 + (size_t)bn * K_;
#pragma unroll
    for (int kk = 0; kk < 6; ++kk) { mk[kk] = ip[wv * 6 + kk]; dd[kk] = dp[wv * 6 + kk]; }
  }

  float base[64];
  {
    float cent[C_];
    const float4* cp = (const float4*)(xt + (size_t)bn * C_);
#pragma unroll
    for (int q = 0; q < 8; ++q) {
      float4 v = cp[q];
      cent[4*q] = v.x; cent[4*q+1] = v.y; cent[4*q+2] = v.z; cent[4*q+3] = v.w;
    }
#pragma unroll 4
    for (int o = 0; o < 64; ++o) {
      float a = 0.f;
#pragma unroll
      for (int c = 0; c < C_; ++c) a = fmaf(cent[c], w1[o * 80 + c], a);
      base[o] = a;
    }
  }

#pragma unroll 1
  for (int kk = 0; kk < 6; ++kk) {
    float row[64];
    {
      const float4* yp = (const float4*)(Y + (size_t)((b << 11) + mk[kk]) * 128);
#pragma unroll
      for (int q = 0; q < 16; ++q) {
        float4 v = yp[q];
        row[4*q] = v.x; row[4*q+1] = v.y; row[4*q+2] = v.z; row[4*q+3] = v.w;
      }
    }
    float dist = sqrtf(fmaxf(dd[kk], 1e-12f));
    float rbf[16];
#pragma unroll
    for (int r = 0; r < 16; ++r) {
      float t = dist - (float)r * (5.0f / 15.0f);
      float e = __expf(-10.f * t * t);
      rbf[r] = fminf(fmaxf(e, 1e-10f), 1.0f);
    }
    float lg = 0.f;
#pragma unroll 2
    for (int o = 0; o < 64; ++o) {
      float acc = base[o] + row[o];
#pragma unroll
      for (int r = 0; r < 16; ++r) acc = fmaf(rbf[r], w1[o * 80 + 64 + r], acc);
      float h = acc > 0.f ? acc : 0.2f * acc;   /* leaky 0.2 */
      lg = fmaf(h, w2[o], lg);
    }
    lgs[lane][wv * 6 + kk] = lg;
  }
  __syncthreads();
  if (wv == 0) {
    float l[K_];
#pragma unroll
    for (int k = 0; k < K_; ++k) l[k] = lgs[lane][k];
    float mx = l[0];
#pragma unroll
    for (int k = 1; k < K_; ++k) mx = fmaxf(mx, l[k]);
    float den = 0.f;
#pragma unroll
    for (int k = 0; k < K_; ++k) { l[k] = __expf(l[k] - mx); den += l[k]; }
    const float inv = 1.f / den;
    float* ap = ws + WS_ATT + (size_t)bn * K_;
#pragma unroll
    for (int k = 0; k < K_; ++k) ap[k] = l[k] * inv;
  }
}

/* ---------------- K2b: BN statistics (wave = point, lane = channel) ------- */
__global__ __launch_bounds__(256, 2) void k2b_stats(float* __restrict__ ws) {
  __shared__ float ls[128];
  const int lane = threadIdx.x & 63;
  const int wv   = __builtin_amdgcn_readfirstlane(threadIdx.x >> 6);
  if (threadIdx.x < 128) ls[threadIdx.x] = 0.f;
  __syncthreads();
  const int w = blockIdx.x * 4 + wv;
  const float* Y = ws + WS_Y;
  float s1 = 0.f, s2 = 0.f;
#pragma unroll 1
  for (int i = 0; i < 16; ++i) {
    const int bn = w * 16 + i;                  /* wave-uniform */
    const int b  = bn >> 11;
    const int*   ip = (const int*)ws + WS_IDX + (size_t)bn * K_;   /* s_load */
    const float* ap = ws + WS_ATT + (size_t)bn * K_;               /* s_load */
#pragma unroll
    for (int k = 0; k < K_; ++k) {
      const int mk = ip[k];
      float yv = Y[(size_t)((b << 11) + mk) * 128 + 64 + lane];    /* coalesced */
      float u = ap[k] * yv;
      s1 += u;
      s2 = fmaf(u, u, s2);
    }
  }
  atomicAdd(&ls[lane], s1);
  atomicAdd(&ls[64 + lane], s2);
  __syncthreads();
  if (threadIdx.x < 128) atomicAdd(ws + WS_ST + threadIdx.x, ls[threadIdx.x]);
}

/* ---------------- K3: finalize BN scale/shift ----------------------------- */
__global__ void k3_bn(const float* __restrict__ gam, const float* __restrict__ bet,
                      float* __restrict__ ws) {
  const int o = threadIdx.x;   /* 64 */
  float s1 = ws[WS_ST + o], s2 = ws[WS_ST + 64 + o];
  const float cnt = (float)BNK_;
  float mean = s1 / cnt;
  float var = fmaxf(s2 / cnt - mean * mean, 0.f);
  float A = gam[o] / sqrtf(var + 1e-5f);
  ws[WS_AB + o] = A;
  ws[WS_AB + 64 + o] = bet[o] - mean * A;
}

/* ---------------- K4: BN apply + leaky + residual + mean_k + store -------- */
__global__ __launch_bounds__(256, 2) void k4_out(const float* __restrict__ resw,
                                                 float* __restrict__ out,
                                                 const float* __restrict__ ws) {
  const int lane = threadIdx.x & 63;
  const int wv   = __builtin_amdgcn_readfirstlane(threadIdx.x >> 6);
  const int w = blockIdx.x * 4 + wv;
  const float* Y  = ws + WS_Y;
  const float* xt = ws + WS_XT;

  float rw[C_];
  {
    const float4* rp = (const float4*)(resw + lane * C_);
#pragma unroll
    for (int q = 0; q < 8; ++q) {
      float4 v = rp[q];
      rw[4*q] = v.x; rw[4*q+1] = v.y; rw[4*q+2] = v.z; rw[4*q+3] = v.w;
    }
  }
  const float A  = ws[WS_AB + lane];
  const float Bb = ws[WS_AB + 64 + lane];
  const int c  = lane & 31;
  const int kh = lane >> 5;

#pragma unroll 1
  for (int i = 0; i < 16; ++i) {
    const int bn = w * 16 + i;                  /* wave-uniform */
    const int b = bn >> 11, n = bn & 2047;
    const int*   ip = (const int*)ws + WS_IDX + (size_t)bn * K_;   /* s_load */
    const float* ap = ws + WS_ATT + (size_t)bn * K_;               /* s_load */

    float facc = 0.f;
#pragma unroll
    for (int k = 0; k < K_; ++k) {
      const int mk = ip[k];
      float yv = Y[(size_t)((b << 11) + mk) * 128 + 64 + lane];    /* coalesced */
      float u = ap[k] * yv;
      float v = fmaf(u, A, Bb);
      v = v > 0.f ? v : 0.02f * v;    /* leaky 0.02 */
      facc += v;
    }
    float sx = 0.f;
#pragma unroll
    for (int kp = 0; kp < 12; ++kp) {
      const int mk = ip[2 * kp + kh];
      sx += xt[(size_t)((b << 11) + mk) * C_ + c];
    }
    float racc = 0.f;
#pragma unroll
    for (int cc = 0; cc < 64; ++cc)
      racc = fmaf(__shfl(sx, cc, 64), rw[cc & 31], racc);

    out[((size_t)(b * 64 + lane)) * N_ + n] = (facc + 0.1f * racc) * (1.f / 24.f);
  }
}

extern "C" void kernel_launch(void* const* d_in, const int* in_sizes, int n_in,
                              void* d_out, int out_size, void* d_ws, size_t ws_size,
                              hipStream_t stream) {
  (void)in_sizes; (void)n_in; (void)out_size; (void)ws_size;
  const float* x    = (const float*)d_in[0];
  /* d_in[1] = idx_base (unused by reference) */
  const float* w1   = (const float*)d_in[2];
  const float* w2   = (const float*)d_in[3];
  const float* updw = (const float*)d_in[4];
  const float* bng  = (const float*)d_in[5];
  const float* bnb  = (const float*)d_in[6];
  const float* resw = (const float*)d_in[7];
  float* out = (float*)d_out;
  float* ws  = (float*)d_ws;

  k0_prep  <<<dim3(128),  dim3(256), 0, stream>>>(x, ws);
  k1a_scan <<<dim3(1024), dim3(256), 0, stream>>>(ws);
  k1b_sel  <<<dim3(512),  dim3(64),  0, stream>>>(ws);
  kY       <<<dim3(256),  dim3(256), 0, stream>>>(w1, updw, ws);
  k2a_att  <<<dim3(512),  dim3(256), 0, stream>>>(w1, w2, ws);
  k2b_stats<<<dim3(512),  dim3(256), 0, stream>>>(ws);
  k3_bn    <<<dim3(1),    dim3(64),  0, stream>>>(bng, bnb, ws);
  k4_out   <<<dim3(512),  dim3(256), 0, stream>>>(resw, out, ws);
}

// Round 8
// 552.925 us; speedup vs baseline: 1.7407x; 1.2056x over previous
//
#include <hip/hip_runtime.h>
#include <math.h>

#define B_   16
#define C_   32
#define N_   2048
#define K_   24
#define BNK_ (B_*N_*K_)      /* 786432 */

/* ws layout (float/int32 units), ~51 MB total */
#define WS_XT   0u           /* xt[b][n][c]  : 1048576 f            */
#define WS_XXD  1048576u     /* xx fp64      : 65536 f              */
#define WS_XXF  1114112u     /* xx fp32      : 32768 f              */
#define WS_IDX  1146880u     /* idx[b][n][k] : 786432 i             */
#define WS_D2   1933312u     /* d2 [b][n][k] : 786432 f             */
#define WS_ATT  2719744u     /* att[b][n][k] : 786432 f             */
#define WS_LOG  3506176u     /* logitsT[k][bn]: 786432 f            */
#define WS_ST   4292608u     /* sum/sumsq    : 128 f                */
#define WS_AB   4292736u     /* BN A,B       : 128 f                */
#define WS_W    4292864u     /* W[m]  att-hist : 32768 f            */
#define WS_W2   4325632u     /* W2[m] att2-hist: 32768 f            */
#define WS_Y    4358400u     /* Y[m][256]: base|attn|upd|res : 8388608 f */
#define WS_L    4358400u     /* k1 lists (aliases Y; dead before kY) */

/* ---------------- K0: transpose x -> xt, row norms, zero stats/W ---------- */
__global__ __launch_bounds__(256) void k0_prep(const float* __restrict__ x,
                                               float* __restrict__ ws) {
  const int i = blockIdx.x;                 /* 128 blocks */
  const int xcd = i & 7, j = i >> 3;
  const int b = 2 * xcd + (j & 1);
  const int half = j >> 1;                  /* 0..7 */
  const int t = (b << 11) + (half << 8) + threadIdx.x;
  const int n = t & 2047;
  const float* xp = x + ((size_t)b * C_ * N_) + n;
  float* xt = ws + WS_XT + (size_t)t * C_;
  double s = 0.0;
#pragma unroll
  for (int c = 0; c < C_; ++c) {
    float v = xp[(size_t)c * N_];
    xt[c] = v;
    s = fma((double)v, (double)v, s);
  }
  ((double*)(ws + WS_XXD))[t] = s;
  ws[WS_XXF + t] = (float)s;
  ws[WS_W + t] = 0.f;
  ws[WS_W2 + t] = 0.f;
  if (t < 128) ws[WS_ST + t] = 0.f;
}

/* ---------------- K1a: fp32 scan of one m-eighth per wave ----------------- */
__global__ __launch_bounds__(256) void k1a_scan(float* __restrict__ ws) {
  const float* xt = ws + WS_XT;
  const int lane = threadIdx.x & 63;
  const int wv   = __builtin_amdgcn_readfirstlane(threadIdx.x >> 6);
  const int i = blockIdx.x;                 /* 1024 blocks */
  const int xcd = i & 7, j = i >> 3;        /* j 0..127 */
  const int b = 2 * xcd + (j & 1);
  const int j2 = j >> 1;                    /* 0..63 */
  const int sub = j2 & 31, epair = j2 >> 5;
  const int pg = (b << 5) + sub;            /* 0..511 */
  const int e  = (epair << 2) | wv;         /* 0..7   */
  const int bn = (b << 11) + (sub << 6) + lane;

  float xn[C_];
  {
    const float4* p = (const float4*)(xt + (size_t)bn * C_);
#pragma unroll
    for (int q = 0; q < 8; ++q) {
      float4 v = p[q];
      xn[4*q] = v.x; xn[4*q+1] = v.y; xn[4*q+2] = v.z; xn[4*q+3] = v.w;
    }
  }

  float val[K_];
#pragma unroll
  for (int j0 = 0; j0 < K_; ++j0) val[j0] = -3.4e38f;

  const float* mrow = xt + ((size_t)((b << 11) + (e << 8))) * C_;  /* uniform */
  const float* xxf  = ws + WS_XXF + (b << 11) + (e << 8);          /* uniform */

#pragma unroll 2
  for (int mm = 0; mm < 256; ++mm) {
    const float* r = mrow + (size_t)mm * C_;   /* wave-uniform -> s_load */
    float a0 = 0.f, a1 = 0.f, a2 = 0.f, a3 = 0.f;
#pragma unroll
    for (int c = 0; c < 8; ++c) {
      a0 = fmaf(xn[c     ], r[c     ], a0);
      a1 = fmaf(xn[c + 8 ], r[c + 8 ], a1);
      a2 = fmaf(xn[c + 16], r[c + 16], a2);
      a3 = fmaf(xn[c + 24], r[c + 24], a3);
    }
    float s = 2.f * ((a0 + a1) + (a2 + a3)) - xxf[mm];
    int sb = (__float_as_int(s) & ~2047) | ((e << 8) + mm);
    float sp = __int_as_float(sb);
#pragma unroll
    for (int j0 = K_ - 1; j0 >= 1; --j0)
      val[j0] = __builtin_amdgcn_fmed3f(val[j0 - 1], val[j0], sp);
    val[0] = fmaxf(val[0], sp);
  }

  float* Lp = ws + WS_L + (((size_t)pg * 8 + e) * K_) * 64 + lane;
#pragma unroll
  for (int j0 = 0; j0 < K_; ++j0) Lp[(size_t)j0 * 64] = val[j0];   /* coalesced */
}

/* ---------------- K1b: union select + exact fp64 re-rank ----------------- */
__global__ __launch_bounds__(64) void k1b_sel(float* __restrict__ ws) {
  const float* xt = ws + WS_XT;
  const double* xxd = (const double*)(ws + WS_XXD);
  const int lane = threadIdx.x & 63;
  const int i = blockIdx.x;                 /* 512 blocks */
  const int xcd = i & 7, j = i >> 3;        /* j 0..63 */
  const int b = 2 * xcd + (j & 1);
  const int sub = j >> 1;                   /* 0..31 */
  const int pg = (b << 5) + sub;
  const int bn = (b << 11) + (sub << 6) + lane;

  float val[32];
#pragma unroll
  for (int j0 = 0; j0 < 32; ++j0) val[j0] = -3.4e38f;
  const float* Lp = ws + WS_L + ((size_t)pg * 8 * K_) * 64 + lane;
#pragma unroll 4
  for (int t = 0; t < 192; ++t) {
    float sp = Lp[(size_t)t * 64];
#pragma unroll
    for (int j0 = 31; j0 >= 1; --j0)
      val[j0] = __builtin_amdgcn_fmed3f(val[j0 - 1], val[j0], sp);
    val[0] = fmaxf(val[0], sp);
  }

  double xnd[C_];
  {
    const float* p = xt + (size_t)bn * C_;
#pragma unroll
    for (int c = 0; c < C_; ++c) xnd[c] = (double)p[c];
  }
  double dl[K_];
#pragma unroll
  for (int j0 = 0; j0 < K_; ++j0) dl[j0] = -1.7e308;

#pragma unroll 1
  for (int j0 = 0; j0 < 32; ++j0) {
    const int m = __float_as_int(val[j0]) & 2047;
    const float* r = xt + ((size_t)((b << 11) + m)) * C_;
    double a0 = 0.0, a1 = 0.0;
#pragma unroll
    for (int c = 0; c < 16; ++c) {
      a0 = fma((double)r[c],      xnd[c],      a0);
      a1 = fma((double)r[c + 16], xnd[c + 16], a1);
    }
    double s = 2.0 * (a0 + a1) - xxd[(b << 11) + m];
    long long bits = (__double_as_longlong(s) & 0xFFFFFFFFFFFFF800ll) | (long long)m;
    double sp = __longlong_as_double(bits);
    if (sp > dl[K_ - 1]) {     /* guarded insert */
      bool c2 = true;
#pragma unroll
      for (int jj = K_ - 1; jj >= 1; --jj) {
        bool c1 = sp > dl[jj - 1];
        dl[jj] = c1 ? dl[jj - 1] : (c2 ? sp : dl[jj]);
        c2 = c1;
      }
      if (c2) dl[0] = sp;
    }
  }

  int*   op = (int*)ws + WS_IDX + (size_t)bn * K_;
  float* dp = ws + WS_D2 + (size_t)bn * K_;
  const double xxn = xxd[bn];
#pragma unroll
  for (int rr = 0; rr < K_; ++rr) {
    long long bl = __double_as_longlong(dl[rr]);
    op[rr] = (int)(bl & 0x7FFll);
    dp[rr] = (float)(xxn - __longlong_as_double(bl & 0xFFFFFFFFFFFFF800ll));
  }
}

/* ---------------- KY: Y[m] = [xt·w1c^T | xt·w1n^T | xt·updw^T | xt·resw^T] */
__global__ __launch_bounds__(128) void kY(const float* __restrict__ w1,
                                          const float* __restrict__ updw,
                                          const float* __restrict__ resw,
                                          float* __restrict__ ws) {
  const int i = blockIdx.x;                 /* 256 blocks x 128 thr */
  const int xcd = i & 7, j = i >> 3;        /* j 0..31 */
  const int b = 2 * xcd + (j & 1);
  const int half = j >> 1;                  /* 0..15 */
  const int p = (b << 11) + (half << 7) + threadIdx.x;
  const float* xt = ws + WS_XT;

  float row[C_];
  {
    const float4* rp = (const float4*)(xt + (size_t)p * C_);
#pragma unroll
    for (int q = 0; q < 8; ++q) {
      float4 v = rp[q];
      row[4*q] = v.x; row[4*q+1] = v.y; row[4*q+2] = v.z; row[4*q+3] = v.w;
    }
  }
  float* yp = ws + WS_Y + (size_t)p * 256;
#pragma unroll 1
  for (int part = 0; part < 4; ++part) {
    const float* W = (part == 0) ? w1 : (part == 1) ? (w1 + 32)
                   : (part == 2) ? updw : resw;          /* uniform */
    const int stride = (part < 2) ? 80 : 32;
#pragma unroll 2
    for (int og = 0; og < 16; ++og) {
      float a[4] = {0.f, 0.f, 0.f, 0.f};
#pragma unroll
      for (int u = 0; u < 4; ++u) {
        const float* wr = W + (4 * og + u) * stride;     /* uniform -> s_load */
#pragma unroll
        for (int c = 0; c < C_; ++c) a[u] = fmaf(row[c], wr[c], a[u]);
      }
      float4 st; st.x = a[0]; st.y = a[1]; st.z = a[2]; st.w = a[3];
      ((float4*)(yp + part * 64))[og] = st;
    }
  }
}

/* ---------------- K2L: logits (wave = (pg,k), lane = point) --------------- */
__global__ __launch_bounds__(256) void k2_logits(const float* __restrict__ w1,
                                                 const float* __restrict__ w2,
                                                 float* __restrict__ ws) {
  const int lane = threadIdx.x & 63;
  const int wv   = __builtin_amdgcn_readfirstlane(threadIdx.x >> 6);
  const int i = blockIdx.x;                 /* 3072 blocks */
  const int xcd = i & 7, j = i >> 3;        /* j 0..383 */
  const int b = 2 * xcd + (j & 1);
  const int slot = ((j >> 1) << 2) + wv;    /* 0..767 */
  const int pgs = (slot * 2731) >> 16;      /* slot/24 */
  const int k = slot - pgs * 24;
  const int bn = (b << 11) + (pgs << 6) + lane;
  const float* Y = ws + WS_Y;

  const int mk  = ((const int*)ws)[WS_IDX + (size_t)bn * K_ + k];
  const float dd = ws[WS_D2 + (size_t)bn * K_ + k];
  float dist = sqrtf(fmaxf(dd, 1e-12f));
  float rbf[16];
#pragma unroll
  for (int r = 0; r < 16; ++r) {
    float t = dist - (float)r * (5.0f / 15.0f);
    float e = __expf(-10.f * t * t);
    rbf[r] = fminf(fmaxf(e, 1e-10f), 1.0f);
  }
  const float4* bp = (const float4*)(Y + (size_t)bn * 256);
  const float4* yp = (const float4*)(Y + (size_t)((b << 11) + mk) * 256 + 64);
  float lg = 0.f;
#pragma unroll 1
  for (int og = 0; og < 4; ++og) {
    float ba[16];
#pragma unroll
    for (int q = 0; q < 4; ++q) {
      float4 v0 = bp[og * 4 + q];
      float4 v1 = yp[og * 4 + q];
      ba[4*q]   = v0.x + v1.x; ba[4*q+1] = v0.y + v1.y;
      ba[4*q+2] = v0.z + v1.z; ba[4*q+3] = v0.w + v1.w;
    }
#pragma unroll
    for (int oo = 0; oo < 16; ++oo) {
      const int o = og * 16 + oo;
      float acc = ba[oo];
#pragma unroll
      for (int r = 0; r < 16; ++r) acc = fmaf(rbf[r], w1[o * 80 + 64 + r], acc);
      float h = acc > 0.f ? acc : 0.2f * acc;   /* leaky 0.2 */
      lg = fmaf(h, w2[o], lg);
    }
  }
  ws[WS_LOG + (size_t)k * 32768 + bn] = lg;     /* coalesced */
}

/* ---------------- K2S: softmax + att + W/W2 scatter-histograms ------------ */
__global__ __launch_bounds__(256) void k2_softmax(float* __restrict__ ws) {
  const int i = blockIdx.x;                 /* 128 blocks */
  const int xcd = i & 7, j = i >> 3;        /* j 0..15 */
  const int b = 2 * xcd + (j & 1);
  const int half = j >> 1;                  /* 0..7 */
  const int bn = (b << 11) + (half << 8) + threadIdx.x;

  float l[K_];
#pragma unroll
  for (int k = 0; k < K_; ++k) l[k] = ws[WS_LOG + (size_t)k * 32768 + bn];
  float mx = l[0];
#pragma unroll
  for (int k = 1; k < K_; ++k) mx = fmaxf(mx, l[k]);
  float den = 0.f;
#pragma unroll
  for (int k = 0; k < K_; ++k) { l[k] = __expf(l[k] - mx); den += l[k]; }
  const float inv = 1.f / den;
#pragma unroll
  for (int k = 0; k < K_; ++k) l[k] *= inv;

  float4* ap = (float4*)(ws + WS_ATT + (size_t)bn * K_);
#pragma unroll
  for (int q = 0; q < 6; ++q) {
    float4 v; v.x = l[4*q]; v.y = l[4*q+1]; v.z = l[4*q+2]; v.w = l[4*q+3];
    ap[q] = v;
  }
  const int* ip = (const int*)ws + WS_IDX + (size_t)bn * K_;
#pragma unroll
  for (int k = 0; k < K_; ++k) {
    const int mk = ip[k];
    atomicAdd(ws + WS_W  + (b << 11) + mk, l[k]);
    atomicAdd(ws + WS_W2 + (b << 11) + mk, l[k] * l[k]);
  }
}

/* ---------------- K2B: BN stats from W/W2 (coalesced sweep) --------------- */
__global__ __launch_bounds__(256) void k2b_stats(float* __restrict__ ws) {
  __shared__ float ls[128];
  const int lane = threadIdx.x & 63;
  const int wv   = __builtin_amdgcn_readfirstlane(threadIdx.x >> 6);
  if (threadIdx.x < 128) ls[threadIdx.x] = 0.f;
  __syncthreads();
  const int i = blockIdx.x;                 /* 128 blocks */
  const int xcd = i & 7, j = i >> 3;
  const int b = 2 * xcd + (j & 1);
  const int half = j >> 1;
  const float* Y = ws + WS_Y;
  float s1 = 0.f, s2 = 0.f;
#pragma unroll 1
  for (int it = 0; it < 64; ++it) {
    const int m = (b << 11) + (half << 8) + (wv << 6) + it;   /* uniform */
    const float w  = ws[WS_W + m];           /* s_load */
    const float w2 = ws[WS_W2 + m];
    const float yv = Y[(size_t)m * 256 + 128 + lane];         /* coalesced */
    s1 = fmaf(w, yv, s1);
    s2 = fmaf(w2, yv * yv, s2);
  }
  atomicAdd(&ls[lane], s1);
  atomicAdd(&ls[64 + lane], s2);
  __syncthreads();
  if (threadIdx.x < 128) atomicAdd(ws + WS_ST + threadIdx.x, ls[threadIdx.x]);
}

/* ---------------- K3: finalize BN scale/shift ----------------------------- */
__global__ void k3_bn(const float* __restrict__ gam, const float* __restrict__ bet,
                      float* __restrict__ ws) {
  const int o = threadIdx.x;   /* 64 */
  float s1 = ws[WS_ST + o], s2 = ws[WS_ST + 64 + o];
  const float cnt = (float)BNK_;
  float mean = s1 / cnt;
  float var = fmaxf(s2 / cnt - mean * mean, 0.f);
  float A = gam[o] / sqrtf(var + 1e-5f);
  ws[WS_AB + o] = A;
  ws[WS_AB + 64 + o] = bet[o] - mean * A;
}

/* ---------------- K4: BN apply + leaky + residual + mean_k + store -------- */
__global__ __launch_bounds__(256) void k4_out(float* __restrict__ out,
                                              const float* __restrict__ ws) {
  __shared__ float tile[32][65];
  const int lane = threadIdx.x & 63;
  const int wv   = __builtin_amdgcn_readfirstlane(threadIdx.x >> 6);
  const int i = blockIdx.x;                 /* 1024 blocks */
  const int xcd = i & 7, j = i >> 3;        /* j 0..127 */
  const int b = 2 * xcd + (j & 1);
  const int j2 = j >> 1;                    /* 0..63 */
  const int n0 = j2 << 5;                   /* 32-point tile */
  const float* Y = ws + WS_Y;
  const float A  = ws[WS_AB + lane];
  const float Bb = ws[WS_AB + 64 + lane];

#pragma unroll 1
  for (int pt = 0; pt < 8; ++pt) {
    const int bn = (b << 11) + n0 + (wv << 3) + pt;           /* uniform */
    const int*   ip = (const int*)ws + WS_IDX + (size_t)bn * K_;   /* s_load */
    const float* ap = ws + WS_ATT + (size_t)bn * K_;               /* s_load */
    float facc = 0.f, racc = 0.f;
#pragma unroll
    for (int k = 0; k < K_; ++k) {
      const int mk = ip[k];
      const float* row = Y + (size_t)((b << 11) + mk) * 256;
      float yv = row[128 + lane];           /* coalesced */
      float rv = row[192 + lane];           /* coalesced */
      float u = ap[k] * yv;
      float v = fmaf(u, A, Bb);
      v = v > 0.f ? v : 0.02f * v;          /* leaky 0.02 */
      facc += v;
      racc += rv;
    }
    tile[(wv << 3) + pt][lane] = (facc + 0.1f * racc) * (1.f / 24.f);
  }
  __syncthreads();
  const int o = threadIdx.x >> 2, q = threadIdx.x & 3;
  float* op = out + ((size_t)(b * 64 + o)) * 2048 + n0 + q * 8;
  float4 v0, v1;
  v0.x = tile[q*8+0][o]; v0.y = tile[q*8+1][o]; v0.z = tile[q*8+2][o]; v0.w = tile[q*8+3][o];
  v1.x = tile[q*8+4][o]; v1.y = tile[q*8+5][o]; v1.z = tile[q*8+6][o]; v1.w = tile[q*8+7][o];
  ((float4*)op)[0] = v0;
  ((float4*)op)[1] = v1;
}

extern "C" void kernel_launch(void* const* d_in, const int* in_sizes, int n_in,
                              void* d_out, int out_size, void* d_ws, size_t ws_size,
                              hipStream_t stream) {
  (void)in_sizes; (void)n_in; (void)out_size; (void)ws_size;
  const float* x    = (const float*)d_in[0];
  /* d_in[1] = idx_base (unused by reference) */
  const float* w1   = (const float*)d_in[2];
  const float* w2   = (const float*)d_in[3];
  const float* updw = (const float*)d_in[4];
  const float* bng  = (const float*)d_in[5];
  const float* bnb  = (const float*)d_in[6];
  const float* resw = (const float*)d_in[7];
  float* out = (float*)d_out;
  float* ws  = (float*)d_ws;

  k0_prep  <<<dim3(128),  dim3(256), 0, stream>>>(x, ws);
  k1a_scan <<<dim3(1024), dim3(256), 0, stream>>>(ws);
  k1b_sel  <<<dim3(512),  dim3(64),  0, stream>>>(ws);
  kY       <<<dim3(256),  dim3(128), 0, stream>>>(w1, updw, resw, ws);
  k2_logits<<<dim3(3072), dim3(256), 0, stream>>>(w1, w2, ws);
  k2_softmax<<<dim3(128), dim3(256), 0, stream>>>(ws);
  k2b_stats<<<dim3(128),  dim3(256), 0, stream>>>(ws);
  k3_bn    <<<dim3(1),    dim3(64),  0, stream>>>(bng, bnb, ws);
  k4_out   <<<dim3(1024), dim3(256), 0, stream>>>(out, ws);
}